// Round 9
// baseline (392.147 us; speedup 1.0000x reference)
//
#include <hip/hip_runtime.h>
#include <hip/hip_bf16.h>

// GCN node encoder: 3 layers GraphConv(norm=both) + residual linear + ReLU + BatchNorm.
// N=50000, E=500000, D=128, L=3.
// Round 9: occupancy push on fused kernel. launch_bounds(256,8) (kernel is 40 VGPR,
// fits 64-cap; LDS 13.8KB*8=110KB<160KB) -> 32 waves/CU for the latency-bound gather.
// NBANK 8->64: 8x fewer global stat-atomic collisions per line. Hot path otherwise
// identical to round 8 (r6 lesson: one auditable change at a time).

#define TPB 256
#define NBANK 64
#define GM 16
#define APAD 136  // 128+8 shorts: 272 B row stride
#define NREP 8    // degree-counter replicas
#define CHUNK 512 // LDS descriptor chunk (avg block needs ~160)

typedef __attribute__((ext_vector_type(8))) short bf16x8;
typedef __attribute__((ext_vector_type(4))) float f32x4;

__device__ inline unsigned short f2bf(float f) {
    unsigned int u = __builtin_bit_cast(unsigned int, f);
    u += 0x7fff + ((u >> 16) & 1);          // RNE
    return (unsigned short)(u >> 16);
}
__device__ inline float bf2f(unsigned short b) {
    unsigned int u = ((unsigned int)b) << 16;
    return __builtin_bit_cast(float, u);
}

// ---------------- prep kernel 1: degree (replicated, batched) + embed + weights ----------------
__global__ void prep1(const int* __restrict__ node_ids, const float* __restrict__ emb,
                      unsigned short* __restrict__ x, int n32,
                      const float* __restrict__ Ws, const float* __restrict__ Rws,
                      unsigned short* __restrict__ Wt, unsigned short* __restrict__ Rwt,
                      int wtotal,
                      const int* __restrict__ src, const int* __restrict__ dst,
                      int* __restrict__ deg_rep, int* __restrict__ rank,
                      int E, int N, int degBlocks) {
    if ((int)blockIdx.x < degBlocks) {
        int rep = blockIdx.x & (NREP - 1);
        int* ds = deg_rep + rep * 2 * N;      // src counters
        int* dd = ds + N;                     // dst counters
        int T = degBlocks * 256;
        int t0 = blockIdx.x * 256 + threadIdx.x;
        int idx[4], sv[4], dv[4];
        #pragma unroll
        for (int k = 0; k < 4; k++) {
            int i = t0 + k * T;
            idx[k] = (i < E) ? i : 0;
        }
        #pragma unroll
        for (int k = 0; k < 4; k++) { sv[k] = src[idx[k]]; dv[k] = dst[idx[k]]; }
        #pragma unroll
        for (int k = 0; k < 4; k++)
            if (t0 + k * T < E) atomicAdd(&ds[sv[k]], 1);
        int r[4];
        #pragma unroll
        for (int k = 0; k < 4; k++)
            r[k] = (t0 + k * T < E) ? atomicAdd(&dd[dv[k]], 1) : 0;
        #pragma unroll
        for (int k = 0; k < 4; k++)
            if (t0 + k * T < E) rank[t0 + k * T] = r[k] | (rep << 24);
    } else {
        int gid = (blockIdx.x - degBlocks) * 256 + threadIdx.x;
        if (gid < n32) {
            int v = gid >> 5, c4 = gid & 31;
            int id = node_ids[v];
            float4 e = *(const float4*)&emb[id * 128 + c4 * 4];
            ushort4 o;
            o.x = f2bf(e.x); o.y = f2bf(e.y); o.z = f2bf(e.z); o.w = f2bf(e.w);
            *(ushort4*)&x[(size_t)v * 128 + c4 * 4] = o;
        }
        if (gid < wtotal) {
            int l = gid >> 14, rr = (gid >> 7) & 127, k = gid & 127;
            int sidx = l * 16384 + k * 128 + rr;
            Wt[gid]  = f2bf(Ws[sidx]);
            Rwt[gid] = f2bf(Rws[sidx]);
        }
    }
}

// sum replicas -> norms; replica counts -> per-node replica prefix offsets;
// block-local exclusive scan of in-degree into row_ptr; block sums to bsum.
__global__ void scan1_norm(int* __restrict__ deg_rep,
                           float* __restrict__ out_norm, float* __restrict__ in_norm,
                           int* __restrict__ row_ptr, int* __restrict__ bsum, int n) {
    __shared__ int tmp[1024];
    int t = threadIdx.x;
    int i = blockIdx.x * 1024 + t;
    int v = 0;
    if (i < n) {
        int dsv = 0, run = 0;
        #pragma unroll
        for (int r = 0; r < NREP; r++) {
            int* base = deg_rep + r * 2 * n;
            dsv += base[i];
            int c = base[n + i];
            base[n + i] = run;   // replica prefix offset for scatter
            run += c;
        }
        v = run;
        out_norm[i] = dsv > 0 ? rsqrtf((float)dsv) : 0.f;
        in_norm[i]  = v   > 0 ? rsqrtf((float)v)   : 0.f;
    }
    tmp[t] = v;
    __syncthreads();
    for (int off = 1; off < 1024; off <<= 1) {
        int add = (t >= off) ? tmp[t - off] : 0;
        __syncthreads();
        tmp[t] += add;
        __syncthreads();
    }
    if (i < n) row_ptr[i] = tmp[t] - v;   // block-local exclusive scan
    if (t == 1023) bsum[blockIdx.x] = tmp[1023];
}

// 1-block: scan bsum -> boff; zero col_un pad
__global__ void boff_scan(const int* __restrict__ bsum, int* __restrict__ boff, int nb,
                          int2* __restrict__ col_un_pad) {
    if (threadIdx.x == 0) {
        int run = 0;
        for (int i = 0; i < nb; i++) { boff[i] = run; run += bsum[i]; }
    }
    if (threadIdx.x < 8) { int2 z; z.x = 0; z.y = 0; col_un_pad[threadIdx.x] = z; }
}

// atomic-free CSR fill with packed (src, out_norm[src]) descriptors; 4 edges/thread
__global__ void scatter_kernel(const int* __restrict__ src, const int* __restrict__ dst,
                               const int* __restrict__ row_ptr, const int* __restrict__ boff,
                               const int* __restrict__ rank,
                               const float* __restrict__ out_norm,
                               const int* __restrict__ deg_rep,
                               int2* __restrict__ col_un, int E, int N, int T) {
    int t0 = blockIdx.x * blockDim.x + threadIdx.x;
    int idx[4], sv[4], dv[4], rk[4];
    #pragma unroll
    for (int k = 0; k < 4; k++) {
        int i = t0 + k * T;
        idx[k] = (i < E) ? i : 0;
    }
    #pragma unroll
    for (int k = 0; k < 4; k++) { sv[k] = src[idx[k]]; dv[k] = dst[idx[k]]; rk[k] = rank[idx[k]]; }
    int pos[4]; float nm[4];
    #pragma unroll
    for (int k = 0; k < 4; k++) {
        int rep = ((unsigned)rk[k]) >> 24;
        int lr = rk[k] & 0xFFFFFF;
        pos[k] = row_ptr[dv[k]] + boff[dv[k] >> 10] + deg_rep[rep * 2 * N + N + dv[k]] + lr;
        nm[k] = out_norm[sv[k]];
    }
    #pragma unroll
    for (int k = 0; k < 4; k++) {
        if (t0 + k * T < E) {
            int2 v; v.x = sv[k]; v.y = __float_as_int(nm[k]);
            col_un[pos[k]] = v;
        }
    }
}

// ---------------- fused per-layer kernel ----------------
// Gather: block's contiguous descriptor range staged to LDS (chunked, coalesced);
//   16 thr/node x 16 nodes; thread owns 8 cols; 8-edge batches with descriptors
//   from LDS broadcast + 8 independent global uint4 row loads.
// MFMA: 4 waves x 2 col-tiles; conv A from As, residual A from Xs, B from Wt/Rwt.
// Epilogue: bias+relu+add -> h (fp32), BN sum/sumsq -> NBANK-banked global stats.
// launch_bounds(256,8): kernel is ~40 VGPR; 8 blocks/CU = 32 waves/CU for the
// latency-bound gather. LDS 13.8KB*8 = 110KB < 160KB.
__global__ __launch_bounds__(256, 8) void fused_layer_kernel(
    const unsigned short* __restrict__ x,
    const int* __restrict__ row_ptr, const int* __restrict__ boff,
    const int2* __restrict__ col_un,
    const float* __restrict__ in_norm,
    const unsigned short* __restrict__ Wt, const unsigned short* __restrict__ Rwt,
    const float* __restrict__ bvec, const float* __restrict__ Rbvec,
    float* __restrict__ h, float* __restrict__ stats, int nrows, int Etot) {
    __shared__ unsigned short As[GM * APAD];
    __shared__ unsigned short Xs[GM * APAD];
    __shared__ int2 Ld[CHUNK];
    __shared__ float bsum[128], bss[128];
    int tid = threadIdx.x;
    int m0 = blockIdx.x * GM;
    if (tid < 128) { bsum[tid] = 0.f; bss[tid] = 0.f; }

    // ---- gather ----
    {
        int node = tid >> 4;
        int part = tid & 15;
        int gnode = m0 + node;
        if (gnode >= nrows) gnode = nrows - 1;
        // stage own x row chunk for residual GEMM
        uint4 xv = *(const uint4*)&x[(size_t)gnode * 128 + part * 8];
        *(uint4*)&Xs[node * APAD + part * 8] = xv;
        float inv = in_norm[gnode];
        int beg = row_ptr[gnode] + boff[gnode >> 10];
        int end = (gnode == nrows - 1) ? Etot
                                       : row_ptr[gnode + 1] + boff[(gnode + 1) >> 10];
        // block's contiguous descriptor range
        int blkBeg = row_ptr[m0] + boff[m0 >> 10];
        int lastN = m0 + GM;
        int blkEnd = (lastN >= nrows) ? Etot : row_ptr[lastN] + boff[lastN >> 10];

        float acc[8];
        #pragma unroll
        for (int j = 0; j < 8; j++) acc[j] = 0.f;
        const unsigned short* xb = x + part * 8;

        for (int chunk = blkBeg; chunk < blkEnd; chunk += CHUNK) {
            int chunkEnd = chunk + CHUNK < blkEnd ? chunk + CHUNK : blkEnd;
            int nd = chunkEnd - chunk;
            __syncthreads();   // previous chunk fully consumed
            for (int i = tid; i < nd; i += TPB) Ld[i] = col_un[chunk + i];
            __syncthreads();
            int e0 = beg > chunk ? beg : chunk;
            int e1 = end < chunkEnd ? end : chunkEnd;
            for (int e = e0; e < e1; e += 8) {
                int rem = e1 - e;
                int base = e - chunk;
                int2 ed[8];
                #pragma unroll
                for (int j = 0; j < 8; j++)
                    ed[j] = Ld[(j < rem) ? (base + j) : base];
                uint4 q[8];
                #pragma unroll
                for (int j = 0; j < 8; j++)
                    q[j] = *(const uint4*)(xb + (size_t)(unsigned)ed[j].x * 128);
                #pragma unroll
                for (int j = 0; j < 8; j++) {
                    float nn = (j < rem) ? __int_as_float(ed[j].y) : 0.f;
                    const unsigned int* w = (const unsigned int*)&q[j];
                    #pragma unroll
                    for (int t = 0; t < 4; t++) {
                        acc[2 * t]     += nn * bf2f((unsigned short)w[t]);
                        acc[2 * t + 1] += nn * bf2f((unsigned short)(w[t] >> 16));
                    }
                }
            }
        }
        #pragma unroll
        for (int j = 0; j < 8; j++) acc[j] *= inv;
        uint4 pk;
        pk.x = (unsigned int)f2bf(acc[0]) | ((unsigned int)f2bf(acc[1]) << 16);
        pk.y = (unsigned int)f2bf(acc[2]) | ((unsigned int)f2bf(acc[3]) << 16);
        pk.z = (unsigned int)f2bf(acc[4]) | ((unsigned int)f2bf(acc[5]) << 16);
        pk.w = (unsigned int)f2bf(acc[6]) | ((unsigned int)f2bf(acc[7]) << 16);
        *(uint4*)&As[node * APAD + part * 8] = pk;
    }
    __syncthreads();

    // ---- dual GEMM via MFMA 16x16x32 bf16 ----
    int wave = tid >> 6;
    int lane = tid & 63;
    int m = lane & 15;
    int quad = lane >> 4;

    f32x4 accA[2], accX[2];
    #pragma unroll
    for (int t = 0; t < 2; t++) { accA[t] = (f32x4){0,0,0,0}; accX[t] = (f32x4){0,0,0,0}; }

    #pragma unroll
    for (int kc = 0; kc < 4; kc++) {
        int koff = kc * 32 + quad * 8;
        bf16x8 aA = *(const bf16x8*)&As[m * APAD + koff];
        bf16x8 aX = *(const bf16x8*)&Xs[m * APAD + koff];
        #pragma unroll
        for (int t = 0; t < 2; t++) {
            int nrow = (wave * 2 + t) * 16 + m;
            bf16x8 bW = *(const bf16x8*)&Wt[(size_t)nrow * 128 + koff];
            bf16x8 bR = *(const bf16x8*)&Rwt[(size_t)nrow * 128 + koff];
            accA[t] = __builtin_amdgcn_mfma_f32_16x16x32_bf16(aA, bW, accA[t], 0, 0, 0);
            accX[t] = __builtin_amdgcn_mfma_f32_16x16x32_bf16(aX, bR, accX[t], 0, 0, 0);
        }
    }

    // ---- epilogue ----
    #pragma unroll
    for (int t = 0; t < 2; t++) {
        int col = (wave * 2 + t) * 16 + m;
        float bW = bvec[col], bR = Rbvec[col];
        float cs = 0.f, cq = 0.f;
        #pragma unroll
        for (int reg = 0; reg < 4; reg++) {
            int gr = m0 + quad * 4 + reg;
            float hA = accA[t][reg] + bW; hA = hA > 0.f ? hA : 0.f;
            float hX = accX[t][reg] + bR; hX = hX > 0.f ? hX : 0.f;
            float v = hA + hX;
            if (gr < nrows) {
                h[(size_t)gr * 128 + col] = v;
            } else {
                v = 0.f;
            }
            cs += v; cq += v * v;
        }
        cs += __shfl_xor(cs, 16); cs += __shfl_xor(cs, 32);
        cq += __shfl_xor(cq, 16); cq += __shfl_xor(cq, 32);
        if (lane < 16) {
            atomicAdd(&bsum[col], cs);
            atomicAdd(&bss[col], cq);
        }
    }
    __syncthreads();
    if (tid < 128) {
        float* sb = stats + (size_t)(blockIdx.x & (NBANK - 1)) * 256;
        atomicAdd(&sb[tid], bsum[tid]);
        atomicAdd(&sb[tid + 128], bss[tid]);
    }
}

// ---------------- BN apply (finalize folded in) ----------------

__global__ void norm_apply_bf16(const float* __restrict__ h, const float* __restrict__ stats,
                                const float* __restrict__ gamma, const float* __restrict__ beta,
                                unsigned short* __restrict__ dstp, int total4, float n) {
    __shared__ float ssc[128], ssh[128];
    int t = threadIdx.x;
    if (t < 128) {
        float s = 0.f, sq = 0.f;
        for (int b2 = 0; b2 < NBANK; b2++) {
            s  += stats[b2 * 256 + t];
            sq += stats[b2 * 256 + t + 128];
        }
        float mu = s / n;
        float var = sq / n - mu * mu;
        float rstd = rsqrtf(var + 1e-5f);
        float sc = gamma[t] * rstd;
        ssc[t] = sc;
        ssh[t] = beta[t] - sc * mu;
    }
    __syncthreads();
    int gid = blockIdx.x * blockDim.x + t;
    if (gid >= total4) return;
    int c4 = gid & 31;
    float4 sc = *(const float4*)&ssc[c4 * 4];
    float4 sh = *(const float4*)&ssh[c4 * 4];
    float4 v = ((const float4*)h)[gid];
    ushort4 o;
    o.x = f2bf(sc.x * v.x + sh.x);
    o.y = f2bf(sc.y * v.y + sh.y);
    o.z = f2bf(sc.z * v.z + sh.z);
    o.w = f2bf(sc.w * v.w + sh.w);
    ((ushort4*)dstp)[gid] = o;
}

__global__ void norm_apply_f32(const float* __restrict__ h, const float* __restrict__ stats,
                               const float* __restrict__ gamma, const float* __restrict__ beta,
                               float* __restrict__ dstp, int total4, float n) {
    __shared__ float ssc[128], ssh[128];
    int t = threadIdx.x;
    if (t < 128) {
        float s = 0.f, sq = 0.f;
        for (int b2 = 0; b2 < NBANK; b2++) {
            s  += stats[b2 * 256 + t];
            sq += stats[b2 * 256 + t + 128];
        }
        float mu = s / n;
        float var = sq / n - mu * mu;
        float rstd = rsqrtf(var + 1e-5f);
        float sc = gamma[t] * rstd;
        ssc[t] = sc;
        ssh[t] = beta[t] - sc * mu;
    }
    __syncthreads();
    int gid = blockIdx.x * blockDim.x + t;
    if (gid >= total4) return;
    int c4 = gid & 31;
    float4 sc = *(const float4*)&ssc[c4 * 4];
    float4 sh = *(const float4*)&ssh[c4 * 4];
    float4 v = ((const float4*)h)[gid];
    float4 o;
    o.x = sc.x * v.x + sh.x;
    o.y = sc.y * v.y + sh.y;
    o.z = sc.z * v.z + sh.z;
    o.w = sc.w * v.w + sh.w;
    ((float4*)dstp)[gid] = o;
}

// ---------------- launch ----------------

extern "C" void kernel_launch(void* const* d_in, const int* in_sizes, int n_in,
                              void* d_out, int out_size, void* d_ws, size_t ws_size,
                              hipStream_t stream) {
    const int*   node_ids = (const int*)d_in[0];
    const int*   src      = (const int*)d_in[1];
    const int*   dst      = (const int*)d_in[2];
    const float* emb      = (const float*)d_in[3];
    const float* Ws       = (const float*)d_in[4];
    const float* bs       = (const float*)d_in[5];
    const float* Rws      = (const float*)d_in[6];
    const float* Rbs      = (const float*)d_in[7];
    const float* gammas   = (const float*)d_in[8];
    const float* betas    = (const float*)d_in[9];

    const int N = in_sizes[0];
    const int E = in_sizes[1];
    const int D = 128;
    const int L = in_sizes[4] / (D * D);

    size_t off = 0;
    auto alloc = [&](size_t bytes) -> void* {
        void* p = (char*)d_ws + off;
        off += (bytes + 255) & ~(size_t)255;
        return p;
    };
    int*   deg_rep  = (int*)alloc((size_t)NREP * 2 * N * 4);
    int*   rank     = (int*)alloc((size_t)E * 4);
    float* out_norm = (float*)alloc((size_t)N * 4);
    float* in_norm  = (float*)alloc((size_t)N * 4);
    int*   row_ptr  = (int*)alloc((size_t)(N + 1) * 4);
    int*   bsumg    = (int*)alloc(64 * 4);
    int*   boffg    = (int*)alloc(64 * 4);
    int2*  col_un   = (int2*)alloc(((size_t)E + 8) * 8);
    float* stats    = (float*)alloc((size_t)L * NBANK * 256 * 4);
    unsigned short* Wt  = (unsigned short*)alloc((size_t)L * D * D * 2);
    unsigned short* Rwt = (unsigned short*)alloc((size_t)L * D * D * 2);
    unsigned short* x   = (unsigned short*)alloc((size_t)N * D * 2);
    float* h = (float*)d_out;  // fp32 h scratch == output buffer

    hipMemsetAsync(deg_rep, 0, (size_t)NREP * 2 * N * 4, stream);
    hipMemsetAsync(stats, 0, (size_t)L * NBANK * 256 * 4, stream);

    int degBlocks = (E + 1023) / 1024;              // 4 edges/thread
    int n32 = N * 32, wtotal = L * D * D;
    int embBlocks = (n32 + TPB - 1) / TPB;
    prep1<<<degBlocks + embBlocks, TPB, 0, stream>>>(
        node_ids, emb, x, n32, Ws, Rws, Wt, Rwt, wtotal,
        src, dst, deg_rep, rank, E, N, degBlocks);

    int nb = (N + 1023) / 1024;
    scan1_norm<<<nb, 1024, 0, stream>>>(deg_rep, out_norm, in_norm, row_ptr, bsumg, N);
    boff_scan<<<1, 64, 0, stream>>>(bsumg, boffg, nb, col_un + E);
    int scatBlocks = (E + 1023) / 1024;
    scatter_kernel<<<scatBlocks, TPB, 0, stream>>>(src, dst, row_ptr, boffg, rank, out_norm,
                                                   deg_rep, col_un, E, N, scatBlocks * 256);

    int gblocks = (N + GM - 1) / GM;
    for (int l = 0; l < L; l++) {
        const unsigned short* Wtl  = Wt  + (size_t)l * D * D;
        const unsigned short* Rwtl = Rwt + (size_t)l * D * D;
        const float* b   = bs  + (size_t)l * D;
        const float* Rb  = Rbs + (size_t)l * D;
        const float* gm  = gammas + (size_t)l * D;
        const float* bt  = betas  + (size_t)l * D;
        float* st = stats + (size_t)l * NBANK * 256;

        fused_layer_kernel<<<gblocks, TPB, 0, stream>>>(
            x, row_ptr, boffg, col_un, in_norm, Wtl, Rwtl, b, Rb, h, st, N, E);
        if (l < L - 1) {
            norm_apply_bf16<<<(N * 32 + TPB - 1) / TPB, TPB, 0, stream>>>(
                h, st, gm, bt, x, N * 32, (float)N);
        } else {
            norm_apply_f32<<<(N * 32 + TPB - 1) / TPB, TPB, 0, stream>>>(
                h, st, gm, bt, (float*)d_out, N * 32, (float)N);
        }
    }
}

// Round 11
// 307.097 us; speedup vs baseline: 1.2769x; 1.2769x over previous
//
#include <hip/hip_runtime.h>
#include <hip/hip_bf16.h>

// GCN node encoder: 3 layers GraphConv(norm=both) + residual linear + ReLU + BatchNorm.
// N=50000, E=500000, D=128, L=3.
// Round 11: exact revert to round-8 (best measured: 308.6 us, absmax 0.0625).
// r8 config is the measured optimum: GM=16, launch_bounds(256,4) (VGPR 40, 8-deep
// load batch stays live), NBANK=8, LDS-staged descriptors. r9 (more occupancy) and
// r10 (cooperative mega-kernel) both failed; r6 (BN fold) regressed.

#define TPB 256
#define NBANK 8
#define GM 16
#define APAD 136  // 128+8 shorts: 272 B row stride
#define NREP 8    // degree-counter replicas
#define CHUNK 512 // LDS descriptor chunk (avg block needs ~160)

typedef __attribute__((ext_vector_type(8))) short bf16x8;
typedef __attribute__((ext_vector_type(4))) float f32x4;

__device__ inline unsigned short f2bf(float f) {
    unsigned int u = __builtin_bit_cast(unsigned int, f);
    u += 0x7fff + ((u >> 16) & 1);          // RNE
    return (unsigned short)(u >> 16);
}
__device__ inline float bf2f(unsigned short b) {
    unsigned int u = ((unsigned int)b) << 16;
    return __builtin_bit_cast(float, u);
}

// ---------------- prep kernel 1: degree (replicated, batched) + embed + weights ----------------
__global__ void prep1(const int* __restrict__ node_ids, const float* __restrict__ emb,
                      unsigned short* __restrict__ x, int n32,
                      const float* __restrict__ Ws, const float* __restrict__ Rws,
                      unsigned short* __restrict__ Wt, unsigned short* __restrict__ Rwt,
                      int wtotal,
                      const int* __restrict__ src, const int* __restrict__ dst,
                      int* __restrict__ deg_rep, int* __restrict__ rank,
                      int E, int N, int degBlocks) {
    if ((int)blockIdx.x < degBlocks) {
        int rep = blockIdx.x & (NREP - 1);
        int* ds = deg_rep + rep * 2 * N;      // src counters
        int* dd = ds + N;                     // dst counters
        int T = degBlocks * 256;
        int t0 = blockIdx.x * 256 + threadIdx.x;
        int idx[4], sv[4], dv[4];
        #pragma unroll
        for (int k = 0; k < 4; k++) {
            int i = t0 + k * T;
            idx[k] = (i < E) ? i : 0;
        }
        #pragma unroll
        for (int k = 0; k < 4; k++) { sv[k] = src[idx[k]]; dv[k] = dst[idx[k]]; }
        #pragma unroll
        for (int k = 0; k < 4; k++)
            if (t0 + k * T < E) atomicAdd(&ds[sv[k]], 1);
        int r[4];
        #pragma unroll
        for (int k = 0; k < 4; k++)
            r[k] = (t0 + k * T < E) ? atomicAdd(&dd[dv[k]], 1) : 0;
        #pragma unroll
        for (int k = 0; k < 4; k++)
            if (t0 + k * T < E) rank[t0 + k * T] = r[k] | (rep << 24);
    } else {
        int gid = (blockIdx.x - degBlocks) * 256 + threadIdx.x;
        if (gid < n32) {
            int v = gid >> 5, c4 = gid & 31;
            int id = node_ids[v];
            float4 e = *(const float4*)&emb[id * 128 + c4 * 4];
            ushort4 o;
            o.x = f2bf(e.x); o.y = f2bf(e.y); o.z = f2bf(e.z); o.w = f2bf(e.w);
            *(ushort4*)&x[(size_t)v * 128 + c4 * 4] = o;
        }
        if (gid < wtotal) {
            int l = gid >> 14, rr = (gid >> 7) & 127, k = gid & 127;
            int sidx = l * 16384 + k * 128 + rr;
            Wt[gid]  = f2bf(Ws[sidx]);
            Rwt[gid] = f2bf(Rws[sidx]);
        }
    }
}

// sum replicas -> norms; replica counts -> per-node replica prefix offsets;
// block-local exclusive scan of in-degree into row_ptr; block sums to bsum.
__global__ void scan1_norm(int* __restrict__ deg_rep,
                           float* __restrict__ out_norm, float* __restrict__ in_norm,
                           int* __restrict__ row_ptr, int* __restrict__ bsum, int n) {
    __shared__ int tmp[1024];
    int t = threadIdx.x;
    int i = blockIdx.x * 1024 + t;
    int v = 0;
    if (i < n) {
        int dsv = 0, run = 0;
        #pragma unroll
        for (int r = 0; r < NREP; r++) {
            int* base = deg_rep + r * 2 * n;
            dsv += base[i];
            int c = base[n + i];
            base[n + i] = run;   // replica prefix offset for scatter
            run += c;
        }
        v = run;
        out_norm[i] = dsv > 0 ? rsqrtf((float)dsv) : 0.f;
        in_norm[i]  = v   > 0 ? rsqrtf((float)v)   : 0.f;
    }
    tmp[t] = v;
    __syncthreads();
    for (int off = 1; off < 1024; off <<= 1) {
        int add = (t >= off) ? tmp[t - off] : 0;
        __syncthreads();
        tmp[t] += add;
        __syncthreads();
    }
    if (i < n) row_ptr[i] = tmp[t] - v;   // block-local exclusive scan
    if (t == 1023) bsum[blockIdx.x] = tmp[1023];
}

// 1-block: scan bsum -> boff; zero col_un pad
__global__ void boff_scan(const int* __restrict__ bsum, int* __restrict__ boff, int nb,
                          int2* __restrict__ col_un_pad) {
    if (threadIdx.x == 0) {
        int run = 0;
        for (int i = 0; i < nb; i++) { boff[i] = run; run += bsum[i]; }
    }
    if (threadIdx.x < 8) { int2 z; z.x = 0; z.y = 0; col_un_pad[threadIdx.x] = z; }
}

// atomic-free CSR fill with packed (src, out_norm[src]) descriptors; 4 edges/thread
__global__ void scatter_kernel(const int* __restrict__ src, const int* __restrict__ dst,
                               const int* __restrict__ row_ptr, const int* __restrict__ boff,
                               const int* __restrict__ rank,
                               const float* __restrict__ out_norm,
                               const int* __restrict__ deg_rep,
                               int2* __restrict__ col_un, int E, int N, int T) {
    int t0 = blockIdx.x * blockDim.x + threadIdx.x;
    int idx[4], sv[4], dv[4], rk[4];
    #pragma unroll
    for (int k = 0; k < 4; k++) {
        int i = t0 + k * T;
        idx[k] = (i < E) ? i : 0;
    }
    #pragma unroll
    for (int k = 0; k < 4; k++) { sv[k] = src[idx[k]]; dv[k] = dst[idx[k]]; rk[k] = rank[idx[k]]; }
    int pos[4]; float nm[4];
    #pragma unroll
    for (int k = 0; k < 4; k++) {
        int rep = ((unsigned)rk[k]) >> 24;
        int lr = rk[k] & 0xFFFFFF;
        pos[k] = row_ptr[dv[k]] + boff[dv[k] >> 10] + deg_rep[rep * 2 * N + N + dv[k]] + lr;
        nm[k] = out_norm[sv[k]];
    }
    #pragma unroll
    for (int k = 0; k < 4; k++) {
        if (t0 + k * T < E) {
            int2 v; v.x = sv[k]; v.y = __float_as_int(nm[k]);
            col_un[pos[k]] = v;
        }
    }
}

// ---------------- fused per-layer kernel ----------------
// Gather: block's contiguous descriptor range staged to LDS (chunked, coalesced);
//   16 thr/node x 16 nodes; thread owns 8 cols; 8-edge batches with descriptors
//   from LDS broadcast + 8 independent global uint4 row loads.
// MFMA: 4 waves x 2 col-tiles; conv A from As, residual A from Xs, B from Wt/Rwt.
// Epilogue: bias+relu+add -> h (fp32), BN sum/sumsq -> NBANK-banked global stats.
// launch_bounds(256,4): measured optimum — VGPR 40 keeps the 8-deep batch live;
// higher occupancy (256,8) regressed (VGPR 32, L2 thrash — r9).
__global__ __launch_bounds__(256, 4) void fused_layer_kernel(
    const unsigned short* __restrict__ x,
    const int* __restrict__ row_ptr, const int* __restrict__ boff,
    const int2* __restrict__ col_un,
    const float* __restrict__ in_norm,
    const unsigned short* __restrict__ Wt, const unsigned short* __restrict__ Rwt,
    const float* __restrict__ bvec, const float* __restrict__ Rbvec,
    float* __restrict__ h, float* __restrict__ stats, int nrows, int Etot) {
    __shared__ unsigned short As[GM * APAD];
    __shared__ unsigned short Xs[GM * APAD];
    __shared__ int2 Ld[CHUNK];
    __shared__ float bsum[128], bss[128];
    int tid = threadIdx.x;
    int m0 = blockIdx.x * GM;
    if (tid < 128) { bsum[tid] = 0.f; bss[tid] = 0.f; }

    // ---- gather ----
    {
        int node = tid >> 4;
        int part = tid & 15;
        int gnode = m0 + node;
        if (gnode >= nrows) gnode = nrows - 1;
        // stage own x row chunk for residual GEMM
        uint4 xv = *(const uint4*)&x[(size_t)gnode * 128 + part * 8];
        *(uint4*)&Xs[node * APAD + part * 8] = xv;
        float inv = in_norm[gnode];
        int beg = row_ptr[gnode] + boff[gnode >> 10];
        int end = (gnode == nrows - 1) ? Etot
                                       : row_ptr[gnode + 1] + boff[(gnode + 1) >> 10];
        // block's contiguous descriptor range
        int blkBeg = row_ptr[m0] + boff[m0 >> 10];
        int lastN = m0 + GM;
        int blkEnd = (lastN >= nrows) ? Etot : row_ptr[lastN] + boff[lastN >> 10];

        float acc[8];
        #pragma unroll
        for (int j = 0; j < 8; j++) acc[j] = 0.f;
        const unsigned short* xb = x + part * 8;

        for (int chunk = blkBeg; chunk < blkEnd; chunk += CHUNK) {
            int chunkEnd = chunk + CHUNK < blkEnd ? chunk + CHUNK : blkEnd;
            int nd = chunkEnd - chunk;
            __syncthreads();   // previous chunk fully consumed
            for (int i = tid; i < nd; i += TPB) Ld[i] = col_un[chunk + i];
            __syncthreads();
            int e0 = beg > chunk ? beg : chunk;
            int e1 = end < chunkEnd ? end : chunkEnd;
            for (int e = e0; e < e1; e += 8) {
                int rem = e1 - e;
                int base = e - chunk;
                int2 ed[8];
                #pragma unroll
                for (int j = 0; j < 8; j++)
                    ed[j] = Ld[(j < rem) ? (base + j) : base];
                uint4 q[8];
                #pragma unroll
                for (int j = 0; j < 8; j++)
                    q[j] = *(const uint4*)(xb + (size_t)(unsigned)ed[j].x * 128);
                #pragma unroll
                for (int j = 0; j < 8; j++) {
                    float nn = (j < rem) ? __int_as_float(ed[j].y) : 0.f;
                    const unsigned int* w = (const unsigned int*)&q[j];
                    #pragma unroll
                    for (int t = 0; t < 4; t++) {
                        acc[2 * t]     += nn * bf2f((unsigned short)w[t]);
                        acc[2 * t + 1] += nn * bf2f((unsigned short)(w[t] >> 16));
                    }
                }
            }
        }
        #pragma unroll
        for (int j = 0; j < 8; j++) acc[j] *= inv;
        uint4 pk;
        pk.x = (unsigned int)f2bf(acc[0]) | ((unsigned int)f2bf(acc[1]) << 16);
        pk.y = (unsigned int)f2bf(acc[2]) | ((unsigned int)f2bf(acc[3]) << 16);
        pk.z = (unsigned int)f2bf(acc[4]) | ((unsigned int)f2bf(acc[5]) << 16);
        pk.w = (unsigned int)f2bf(acc[6]) | ((unsigned int)f2bf(acc[7]) << 16);
        *(uint4*)&As[node * APAD + part * 8] = pk;
    }
    __syncthreads();

    // ---- dual GEMM via MFMA 16x16x32 bf16 ----
    int wave = tid >> 6;
    int lane = tid & 63;
    int m = lane & 15;
    int quad = lane >> 4;

    f32x4 accA[2], accX[2];
    #pragma unroll
    for (int t = 0; t < 2; t++) { accA[t] = (f32x4){0,0,0,0}; accX[t] = (f32x4){0,0,0,0}; }

    #pragma unroll
    for (int kc = 0; kc < 4; kc++) {
        int koff = kc * 32 + quad * 8;
        bf16x8 aA = *(const bf16x8*)&As[m * APAD + koff];
        bf16x8 aX = *(const bf16x8*)&Xs[m * APAD + koff];
        #pragma unroll
        for (int t = 0; t < 2; t++) {
            int nrow = (wave * 2 + t) * 16 + m;
            bf16x8 bW = *(const bf16x8*)&Wt[(size_t)nrow * 128 + koff];
            bf16x8 bR = *(const bf16x8*)&Rwt[(size_t)nrow * 128 + koff];
            accA[t] = __builtin_amdgcn_mfma_f32_16x16x32_bf16(aA, bW, accA[t], 0, 0, 0);
            accX[t] = __builtin_amdgcn_mfma_f32_16x16x32_bf16(aX, bR, accX[t], 0, 0, 0);
        }
    }

    // ---- epilogue ----
    #pragma unroll
    for (int t = 0; t < 2; t++) {
        int col = (wave * 2 + t) * 16 + m;
        float bW = bvec[col], bR = Rbvec[col];
        float cs = 0.f, cq = 0.f;
        #pragma unroll
        for (int reg = 0; reg < 4; reg++) {
            int gr = m0 + quad * 4 + reg;
            float hA = accA[t][reg] + bW; hA = hA > 0.f ? hA : 0.f;
            float hX = accX[t][reg] + bR; hX = hX > 0.f ? hX : 0.f;
            float v = hA + hX;
            if (gr < nrows) {
                h[(size_t)gr * 128 + col] = v;
            } else {
                v = 0.f;
            }
            cs += v; cq += v * v;
        }
        cs += __shfl_xor(cs, 16); cs += __shfl_xor(cs, 32);
        cq += __shfl_xor(cq, 16); cq += __shfl_xor(cq, 32);
        if (lane < 16) {
            atomicAdd(&bsum[col], cs);
            atomicAdd(&bss[col], cq);
        }
    }
    __syncthreads();
    if (tid < 128) {
        float* sb = stats + (size_t)(blockIdx.x & (NBANK - 1)) * 256;
        atomicAdd(&sb[tid], bsum[tid]);
        atomicAdd(&sb[tid + 128], bss[tid]);
    }
}

// ---------------- BN apply (finalize folded in) ----------------

__global__ void norm_apply_bf16(const float* __restrict__ h, const float* __restrict__ stats,
                                const float* __restrict__ gamma, const float* __restrict__ beta,
                                unsigned short* __restrict__ dstp, int total4, float n) {
    __shared__ float ssc[128], ssh[128];
    int t = threadIdx.x;
    if (t < 128) {
        float s = 0.f, sq = 0.f;
        #pragma unroll
        for (int b2 = 0; b2 < NBANK; b2++) {
            s  += stats[b2 * 256 + t];
            sq += stats[b2 * 256 + t + 128];
        }
        float mu = s / n;
        float var = sq / n - mu * mu;
        float rstd = rsqrtf(var + 1e-5f);
        float sc = gamma[t] * rstd;
        ssc[t] = sc;
        ssh[t] = beta[t] - sc * mu;
    }
    __syncthreads();
    int gid = blockIdx.x * blockDim.x + t;
    if (gid >= total4) return;
    int c4 = gid & 31;
    float4 sc = *(const float4*)&ssc[c4 * 4];
    float4 sh = *(const float4*)&ssh[c4 * 4];
    float4 v = ((const float4*)h)[gid];
    ushort4 o;
    o.x = f2bf(sc.x * v.x + sh.x);
    o.y = f2bf(sc.y * v.y + sh.y);
    o.z = f2bf(sc.z * v.z + sh.z);
    o.w = f2bf(sc.w * v.w + sh.w);
    ((ushort4*)dstp)[gid] = o;
}

__global__ void norm_apply_f32(const float* __restrict__ h, const float* __restrict__ stats,
                               const float* __restrict__ gamma, const float* __restrict__ beta,
                               float* __restrict__ dstp, int total4, float n) {
    __shared__ float ssc[128], ssh[128];
    int t = threadIdx.x;
    if (t < 128) {
        float s = 0.f, sq = 0.f;
        #pragma unroll
        for (int b2 = 0; b2 < NBANK; b2++) {
            s  += stats[b2 * 256 + t];
            sq += stats[b2 * 256 + t + 128];
        }
        float mu = s / n;
        float var = sq / n - mu * mu;
        float rstd = rsqrtf(var + 1e-5f);
        float sc = gamma[t] * rstd;
        ssc[t] = sc;
        ssh[t] = beta[t] - sc * mu;
    }
    __syncthreads();
    int gid = blockIdx.x * blockDim.x + t;
    if (gid >= total4) return;
    int c4 = gid & 31;
    float4 sc = *(const float4*)&ssc[c4 * 4];
    float4 sh = *(const float4*)&ssh[c4 * 4];
    float4 v = ((const float4*)h)[gid];
    float4 o;
    o.x = sc.x * v.x + sh.x;
    o.y = sc.y * v.y + sh.y;
    o.z = sc.z * v.z + sh.z;
    o.w = sc.w * v.w + sh.w;
    ((float4*)dstp)[gid] = o;
}

// ---------------- launch ----------------

extern "C" void kernel_launch(void* const* d_in, const int* in_sizes, int n_in,
                              void* d_out, int out_size, void* d_ws, size_t ws_size,
                              hipStream_t stream) {
    const int*   node_ids = (const int*)d_in[0];
    const int*   src      = (const int*)d_in[1];
    const int*   dst      = (const int*)d_in[2];
    const float* emb      = (const float*)d_in[3];
    const float* Ws       = (const float*)d_in[4];
    const float* bs       = (const float*)d_in[5];
    const float* Rws      = (const float*)d_in[6];
    const float* Rbs      = (const float*)d_in[7];
    const float* gammas   = (const float*)d_in[8];
    const float* betas    = (const float*)d_in[9];

    const int N = in_sizes[0];
    const int E = in_sizes[1];
    const int D = 128;
    const int L = in_sizes[4] / (D * D);

    size_t off = 0;
    auto alloc = [&](size_t bytes) -> void* {
        void* p = (char*)d_ws + off;
        off += (bytes + 255) & ~(size_t)255;
        return p;
    };
    int*   deg_rep  = (int*)alloc((size_t)NREP * 2 * N * 4);
    int*   rank     = (int*)alloc((size_t)E * 4);
    float* out_norm = (float*)alloc((size_t)N * 4);
    float* in_norm  = (float*)alloc((size_t)N * 4);
    int*   row_ptr  = (int*)alloc((size_t)(N + 1) * 4);
    int*   bsumg    = (int*)alloc(64 * 4);
    int*   boffg    = (int*)alloc(64 * 4);
    int2*  col_un   = (int2*)alloc(((size_t)E + 8) * 8);
    float* stats    = (float*)alloc((size_t)L * NBANK * 256 * 4);
    unsigned short* Wt  = (unsigned short*)alloc((size_t)L * D * D * 2);
    unsigned short* Rwt = (unsigned short*)alloc((size_t)L * D * D * 2);
    unsigned short* x   = (unsigned short*)alloc((size_t)N * D * 2);
    float* h = (float*)d_out;  // fp32 h scratch == output buffer

    hipMemsetAsync(deg_rep, 0, (size_t)NREP * 2 * N * 4, stream);
    hipMemsetAsync(stats, 0, (size_t)L * NBANK * 256 * 4, stream);

    int degBlocks = (E + 1023) / 1024;              // 4 edges/thread
    int n32 = N * 32, wtotal = L * D * D;
    int embBlocks = (n32 + TPB - 1) / TPB;
    prep1<<<degBlocks + embBlocks, TPB, 0, stream>>>(
        node_ids, emb, x, n32, Ws, Rws, Wt, Rwt, wtotal,
        src, dst, deg_rep, rank, E, N, degBlocks);

    int nb = (N + 1023) / 1024;
    scan1_norm<<<nb, 1024, 0, stream>>>(deg_rep, out_norm, in_norm, row_ptr, bsumg, N);
    boff_scan<<<1, 64, 0, stream>>>(bsumg, boffg, nb, col_un + E);
    int scatBlocks = (E + 1023) / 1024;
    scatter_kernel<<<scatBlocks, TPB, 0, stream>>>(src, dst, row_ptr, boffg, rank, out_norm,
                                                   deg_rep, col_un, E, N, scatBlocks * 256);

    int gblocks = (N + GM - 1) / GM;
    for (int l = 0; l < L; l++) {
        const unsigned short* Wtl  = Wt  + (size_t)l * D * D;
        const unsigned short* Rwtl = Rwt + (size_t)l * D * D;
        const float* b   = bs  + (size_t)l * D;
        const float* Rb  = Rbs + (size_t)l * D;
        const float* gm  = gammas + (size_t)l * D;
        const float* bt  = betas  + (size_t)l * D;
        float* st = stats + (size_t)l * NBANK * 256;

        fused_layer_kernel<<<gblocks, TPB, 0, stream>>>(
            x, row_ptr, boffg, col_un, in_norm, Wtl, Rwtl, b, Rb, h, st, N, E);
        if (l < L - 1) {
            norm_apply_bf16<<<(N * 32 + TPB - 1) / TPB, TPB, 0, stream>>>(
                h, st, gm, bt, x, N * 32, (float)N);
        } else {
            norm_apply_f32<<<(N * 32 + TPB - 1) / TPB, TPB, 0, stream>>>(
                h, st, gm, bt, (float*)d_out, N * 32, (float)N);
        }
    }
}